// Round 13
// baseline (905.004 us; speedup 1.0000x reference)
//
#include <hip/hip_runtime.h>

// LSTM B=512 T=1024 H=150 I=1 + Linear(150->1) + sigmoid.
// ROUND-13: intra-wave MFMA/PW overlap. r12 postmortem: per-SIMD matrix pipe
//   = 200 instr/4 x 16cyc = 800 cyc/step (MfmaUtil 38% active) and step 2153
//   = near-zero overlap between MFMA phase and PW/LDS phases (barrier convoy).
//   Fix: 4 waves (1/SIMD), each owns 9-10 tiles (stride-4: wid+4j) in 3
//   merge-groups of 4; source order MFMA(g0),MFMA(g1),PW(g0),MFMA(g2),PW(g1),
//   PW(g2): each PW's ~70 VALU/trans issue under the next group's 320-cyc
//   MFMA pipe occupancy. In-order issue in ONE wave = deterministic overlap.
// Keeps r12's wins: merge-4 (4 seqs, 128 blocks), stride-176 (2-way banks).
// waves_per_eu(1,1): 512-reg budget for wf(200)+acc(40)+bf(20)+misc (~295).
// M = 640 vrows (4*cell+gate), 38 tiles; vrow 600 (tile 37 row 8) = W_out.
// K = 160: k<150 = h (LDS dbuf), k=150 = 1.0 (bias), k=151 = x_t, rest 0.
// Weights pre-scaled by -log2e / +2log2e: PW = 5 exp2 + 2 rcp per cell.

typedef _Float16 half8 __attribute__((ext_vector_type(8)));
typedef float f32x4 __attribute__((ext_vector_type(4)));

#define LOG2E 1.44269504088896340736f
#define TWOLOG2E 2.88539008177792681472f

// pointwise+write for merge-group G (uses acc[4G..4G+3], cst[G], wen[G])
#define PW_GROUP(G)                                                          \
  {                                                                          \
    const bool s1 = (b & 4) != 0, s2 = (b & 8) != 0;                         \
    f32x4 gg;                                                                \
    _Pragma("unroll")                                                        \
    for (int r = 0; r < 4; ++r) {                                            \
      const float v01 = s1 ? acc[4*(G)+1][r] : acc[4*(G)+0][r];              \
      const float v23 = s1 ? acc[4*(G)+3][r] : acc[4*(G)+2][r];              \
      gg[r] = s2 ? v23 : v01;                                                \
    }                                                                        \
    const float ei = __builtin_amdgcn_exp2f(gg[0]);                          \
    const float ef = __builtin_amdgcn_exp2f(gg[1]);                          \
    const float eg = __builtin_amdgcn_exp2f(gg[2]);                          \
    const float eo = __builtin_amdgcn_exp2f(gg[3]);                          \
    const float A   = 1.0f + ei;      /* 1/i */                              \
    const float F   = 1.0f + ef;      /* 1/f */                              \
    const float G1  = eg + 1.0f;                                             \
    const float Gm  = eg - 1.0f;      /* g = Gm/G1 */                        \
    const float AG  = A * G1;                                                \
    const float num = fmaf(cst[G], AG, Gm * F);                              \
    const float cn  = num * __builtin_amdgcn_rcpf(F * AG);                   \
    cst[G] = cn;                                                             \
    const float ec = __builtin_amdgcn_exp2f(TWOLOG2E * cn);                  \
    const float hv = (ec - 1.0f) *                                           \
                     __builtin_amdgcn_rcpf((1.0f + eo) * (ec + 1.0f));       \
    if (wen[G]) {                                                            \
      _Float16* w = nxt ? wpB[G] : wpA[G];                                   \
      *w = (_Float16)hv;                                                     \
    }                                                                        \
  }

__global__
__attribute__((amdgpu_flat_work_group_size(256, 256), amdgpu_waves_per_eu(1, 1)))
void lstm_kernel(
    const float* __restrict__ x,      // [512][1024]
    const float* __restrict__ W_ih,   // [600]
    const float* __restrict__ W_hh,   // [600][150]
    const float* __restrict__ b_ih,   // [600]
    const float* __restrict__ b_hh,   // [600]
    const float* __restrict__ W_out,  // [150]
    const float* __restrict__ b_out,  // [1]
    float* __restrict__ out)          // [512][1024]
{
  const int tid  = threadIdx.x;
  const int wid  = tid >> 6;
  const int lane = tid & 63;
  const int q    = lane >> 4;   // k-subchunk for A/B frags; cell offset for D
  const int b    = lane & 15;   // D col; A-frag row m
  const int br   = b & 3;       // real batch (cols duplicate mod 4)
  const int e    = b >> 2;      // merged-tile selector
  const int bid  = blockIdx.x;

  // stride 176 f16 = 88 dwords: reads 2-way banked (free), writes spread
  __shared__ __align__(16) _Float16 hbuf[2][4][176];
  __shared__ _Float16 xlds[4][1032];

  // ---- prologue ----
  for (int i = tid; i < 2*4*176; i += 256)
    (&hbuf[0][0][0])[i] = (_Float16)0.0f;
  {
    const float4* x4 = (const float4*)(x + (size_t)bid * 4 * 1024);
    for (int i = tid; i < 4*256; i += 256) {
      int row = i >> 8, c4 = i & 255;
      float4 v = x4[row*256 + c4];
      xlds[row][c4*4+0] = (_Float16)v.x;
      xlds[row][c4*4+1] = (_Float16)v.y;
      xlds[row][c4*4+2] = (_Float16)v.z;
      xlds[row][c4*4+3] = (_Float16)v.w;
    }
  }
  __syncthreads();
  if (tid < 8) hbuf[tid>>2][tid&3][150] = (_Float16)1.0f;  // bias col, both bufs
  if (tid < 4) hbuf[0][tid][151] = xlds[tid][0];           // x_0
  __syncthreads();

  // ---- tile ownership: wave w -> tiles {w + 4j : j=0..NT-1}, NT = 10/10/9/9 ----
  const int NT = (wid < 2) ? 10 : 9;

  // ---- weight fragments: wf[slot][chunk], up to 10x5 half8 = 200 VGPR ----
  const float bo = b_out[0];
  half8 wf[10][5];
#pragma unroll
  for (int j = 0; j < 10; ++j) {
#pragma unroll
    for (int s = 0; s < 5; ++s) wf[j][s] = (half8)(_Float16)0.0f;
    if (j < NT) {
      const int tg   = wid + 4*j;
      const int vrow = tg*16 + b;          // A-frag: m = lane&15
      const int cell = vrow >> 2, gate = vrow & 3;
      const float alpha = (gate == 2) ? TWOLOG2E : -LOG2E;
#pragma unroll
      for (int s = 0; s < 5; ++s) {
        half8 v;
#pragma unroll
        for (int jj = 0; jj < 8; ++jj) {
          const int k = s*32 + q*8 + jj;   // same (q,j)->k map as B frags
          float w = 0.0f;
          if (vrow == 600) {               // out row
            if (k < 150)       w = -LOG2E * W_out[k];
            else if (k == 150) w = -LOG2E * bo;
          } else if (cell < 150) {
            const int orow = gate*150 + cell;
            if (k < 150)       w = alpha * W_hh[orow*150 + k];
            else if (k == 150) w = alpha * (b_ih[orow] + b_hh[orow]);
            else if (k == 151) w = alpha * W_ih[orow];
          }
          v[jj] = (_Float16)w;
        }
        wf[j][s] = v;
      }
    }
  }

  float cst[3] = {0.f, 0.f, 0.f};  // merged-lane c state, one per group

  // write targets: group g -> tile wid+16g+4e, cell = 4*tile + q
  bool wen[3];
  _Float16 *wpA[3], *wpB[3];
#pragma unroll
  for (int g = 0; g < 3; ++g) {
    const int slot = 4*g + e;
    const int cell = 4*(wid + 16*g + 4*e) + q;
    wen[g] = (slot < NT) && (cell < 150);
    const int wc = wen[g] ? cell : 152;    // clamped; writes guarded
    wpA[g] = &hbuf[0][br][wc];
    wpB[g] = &hbuf[1][br][wc];
  }
  const bool is_out = (wid == 1) && (q == 2) && (b < 4);  // tile37 row8 reg0
  const bool is_x   = (wid == 3) && (q == 0) && (b < 4);
  float* outp = out + ((size_t)bid*4 + br) * 1024;

  const _Float16* rb0 = &hbuf[0][br][q*8];
  const _Float16* rb1 = &hbuf[1][br][q*8];

  int cur = 0;
  for (int t = 0; t <= 1024; ++t) {
    const int nxt = cur ^ 1;
    _Float16 xv = (_Float16)0.0f;
    if (is_x && t < 1023) xv = xlds[b][t+1];

    const _Float16* r0 = cur ? rb1 : rb0;
    half8 bf[5];
#pragma unroll
    for (int s = 0; s < 5; ++s)
      bf[s] = *(const half8*)(r0 + s*32);

    f32x4 acc[10];
#pragma unroll
    for (int j = 0; j < 10; ++j) acc[j] = (f32x4){0.f, 0.f, 0.f, 0.f};

    // ---- MFMA group 0 (slots 0-3) ----
#pragma unroll
    for (int j = 0; j < 4; ++j)
#pragma unroll
      for (int s = 0; s < 5; ++s)
        acc[j] = __builtin_amdgcn_mfma_f32_16x16x32_f16(wf[j][s], bf[s], acc[j], 0,0,0);
    // ---- MFMA group 1 (slots 4-7) ----
#pragma unroll
    for (int j = 4; j < 8; ++j)
#pragma unroll
      for (int s = 0; s < 5; ++s)
        acc[j] = __builtin_amdgcn_mfma_f32_16x16x32_f16(wf[j][s], bf[s], acc[j], 0,0,0);

    // ---- PW group 0 issues while group-1 MFMAs occupy the matrix pipe ----
    PW_GROUP(0)

    // ---- MFMA group 2 (slots 8, 9) ----
#pragma unroll
    for (int s = 0; s < 5; ++s)
      acc[8] = __builtin_amdgcn_mfma_f32_16x16x32_f16(wf[8][s], bf[s], acc[8], 0,0,0);
    if (NT == 10) {
#pragma unroll
      for (int s = 0; s < 5; ++s)
        acc[9] = __builtin_amdgcn_mfma_f32_16x16x32_f16(wf[9][s], bf[s], acc[9], 0,0,0);
    }

    // ---- PW group 1 issues under group-2 MFMAs ----
    PW_GROUP(1)

    // out_{t-1} = sigmoid(Wout.h_{t-1} + b_out); wave1 slot9 = tile 37, reg 0
    if (is_out && t >= 1)
      outp[t-1] = __builtin_amdgcn_rcpf(1.0f + __builtin_amdgcn_exp2f(acc[9][0]));
    if (t == 1024) break;

    PW_GROUP(2)

    if (is_x && t < 1023) hbuf[nxt][b][151] = xv;  // x_{t+1}
    __syncthreads();
    cur = nxt;
  }
}

extern "C" void kernel_launch(void* const* d_in, const int* in_sizes, int n_in,
                              void* d_out, int out_size, void* d_ws, size_t ws_size,
                              hipStream_t stream) {
  const float* x     = (const float*)d_in[0];
  const float* W_ih  = (const float*)d_in[1];
  const float* W_hh  = (const float*)d_in[2];
  const float* b_ih  = (const float*)d_in[3];
  const float* b_hh  = (const float*)d_in[4];
  const float* W_out = (const float*)d_in[5];
  const float* b_out = (const float*)d_in[6];
  lstm_kernel<<<dim3(128), dim3(256), 0, stream>>>(
      x, W_ih, W_hh, b_ih, b_hh, W_out, b_out, (float*)d_out);
}

// Round 14
// 700.610 us; speedup vs baseline: 1.2917x; 1.2917x over previous
//
#include <hip/hip_runtime.h>

// LSTM B=512 T=1024 H=150 I=1 + Linear(150->1) + sigmoid.
// ROUND-14: 256 blocks x 2 seqs (ALL CUs), merge-5 PW, setprio on MFMA.
//   r12 step = 2000 cyc == serial sum {matrix 800 + VALU/trans 650 + LDS 480}
//   (barrier convoy, no overlap; r13 proved intra-wave MFMA||VALU impossible
//   -> MFMA blocks its wave; m114: overlap is cross-wave only).
//   - 2 seqs/block halves VALU/trans per CU again: each wave owns 5 tiles
//     (stride-8: wid+8j), lane e=b>>1 selects gates -> ONE merged PW set
//     per wave (7 trans instr). Matrix/LDS per CU invariant.
//   - s_setprio(1) around MFMA chain (T5): LDS-serialization skews waves;
//     priority keeps matrix pipe fed while skewed waves run PW on VALU.
//   - uniform 25 MFMA/wave (zero-padded wf for waves 6,7) -> balanced SIMDs.
// M = 640 vrows (4*cell+gate), 38 tiles; vrow 600 (tile 37 row 8) = W_out.
// K = 160: k<150 = h (LDS dbuf), k=150 = 1.0 (bias), k=151 = x_t, rest 0.
// Weights pre-scaled by -log2e / +2log2e: PW = 5 exp2 + 2 rcp per cell.

typedef _Float16 half8 __attribute__((ext_vector_type(8)));
typedef float f32x4 __attribute__((ext_vector_type(4)));

#define LOG2E 1.44269504088896340736f
#define TWOLOG2E 2.88539008177792681472f

__global__
__attribute__((amdgpu_flat_work_group_size(512, 512), amdgpu_waves_per_eu(2, 2)))
void lstm_kernel(
    const float* __restrict__ x,      // [512][1024]
    const float* __restrict__ W_ih,   // [600]
    const float* __restrict__ W_hh,   // [600][150]
    const float* __restrict__ b_ih,   // [600]
    const float* __restrict__ b_hh,   // [600]
    const float* __restrict__ W_out,  // [150]
    const float* __restrict__ b_out,  // [1]
    float* __restrict__ out)          // [512][1024]
{
  const int tid  = threadIdx.x;
  const int wid  = tid >> 6;
  const int lane = tid & 63;
  const int q    = lane >> 4;   // k-subchunk for A/B frags; cell offset for D
  const int b    = lane & 15;   // D col; A-frag row m
  const int br   = b & 1;       // real batch (cols duplicate mod 2)
  const int bid  = blockIdx.x;

  // stride 168 f16 = 84 dw: 2-row read pattern overlaps on 1 bank span only
  __shared__ __align__(16) _Float16 hbuf[2][2][168];
  __shared__ _Float16 xlds[2][1032];

  // ---- prologue: zero hbuf, stage x (2 rows x 1024 = 512 float4) ----
  for (int i = tid; i < 2*2*168; i += 512)
    (&hbuf[0][0][0])[i] = (_Float16)0.0f;
  {
    const float4* x4 = (const float4*)(x + (size_t)bid * 2 * 1024);
    const int row = tid >> 8, c4 = tid & 255;
    float4 v = x4[row*256 + c4];
    xlds[row][c4*4+0] = (_Float16)v.x;
    xlds[row][c4*4+1] = (_Float16)v.y;
    xlds[row][c4*4+2] = (_Float16)v.z;
    xlds[row][c4*4+3] = (_Float16)v.w;
  }
  __syncthreads();
  if (tid < 4) hbuf[tid>>1][tid&1][150] = (_Float16)1.0f;  // bias col, both bufs
  if (tid < 2) hbuf[0][tid][151] = xlds[tid][0];           // x_0
  __syncthreads();

  // ---- tile ownership: wave w -> {w + 8j, j<NT}; NT = 5 (w<6) else 4 ----
  const int NT = (wid < 6) ? 5 : 4;

  // ---- weight fragments: 5 tiles x 5 chunks = 100 VGPR (zeros past NT) ----
  const float bo = b_out[0];
  half8 wf[5][5];
#pragma unroll
  for (int j = 0; j < 5; ++j) {
#pragma unroll
    for (int s = 0; s < 5; ++s) wf[j][s] = (half8)(_Float16)0.0f;
    if (j < NT) {
      const int tg   = wid + 8*j;
      const int vrow = tg*16 + b;          // A-frag: m = lane&15
      const int cell = vrow >> 2, gate = vrow & 3;
      const float alpha = (gate == 2) ? TWOLOG2E : -LOG2E;
#pragma unroll
      for (int s = 0; s < 5; ++s) {
        half8 v;
#pragma unroll
        for (int jj = 0; jj < 8; ++jj) {
          const int k = s*32 + q*8 + jj;   // same (q,j)->k map as B frags
          float w = 0.0f;
          if (vrow == 600) {               // out row
            if (k < 150)       w = -LOG2E * W_out[k];
            else if (k == 150) w = -LOG2E * bo;
          } else if (cell < 150) {
            const int orow = gate*150 + cell;
            if (k < 150)       w = alpha * W_hh[orow*150 + k];
            else if (k == 150) w = alpha * (b_ih[orow] + b_hh[orow]);
            else if (k == 151) w = alpha * W_ih[orow];
          }
          v[jj] = (_Float16)w;
        }
        wf[j][s] = v;
      }
    }
  }

  float cst = 0.f;                 // one cell per lane
  const int  e     = b >> 1;       // merged-tile selector (0..7; >=5 junk)
  const int  cell  = 4*(wid + 8*e) + q;
  const bool wen   = (e < NT) && (cell < 150);
  const int  wc    = wen ? cell : 152;   // clamp (pointer never used if !wen)
  const bool is_x  = (wid == 7) && (q == 0) && (b < 2);
  const bool is_out= (wid == 5) && (q == 2) && (b < 2);  // tile37 row 8, reg 0
  float* outp = out + ((size_t)bid*2 + br) * 1024;

  const _Float16* rb0 = &hbuf[0][br][q*8];
  const _Float16* rb1 = &hbuf[1][br][q*8];
  _Float16* wp0 = &hbuf[0][br][wc];
  _Float16* wp1 = &hbuf[1][br][wc];
  _Float16* xw0 = &hbuf[0][br][151];
  _Float16* xw1 = &hbuf[1][br][151];

  for (int t = 0; t <= 1024; ++t) {
    _Float16 xv = (_Float16)0.0f;
    if (is_x && t < 1023) xv = xlds[b][t+1];   // issued early, used post-PW

    const _Float16* r0 = (t & 1) ? rb1 : rb0;
    f32x4 acc[5];
#pragma unroll
    for (int j = 0; j < 5; ++j) acc[j] = (f32x4){0.f, 0.f, 0.f, 0.f};

    __builtin_amdgcn_s_setprio(1);
#pragma unroll
    for (int s = 0; s < 5; ++s) {
      const half8 bfs = *(const half8*)(r0 + s*32);
#pragma unroll
      for (int j = 0; j < 5; ++j)
        acc[j] = __builtin_amdgcn_mfma_f32_16x16x32_f16(wf[j][s], bfs, acc[j], 0,0,0);
    }
    __builtin_amdgcn_s_setprio(0);

    // out_{t-1} = sigmoid(Wout.h_{t-1} + b_out); tile 37 = wid5 slot 4, reg 0
    if (is_out && t >= 1)
      outp[t-1] = __builtin_amdgcn_rcpf(1.0f + __builtin_amdgcn_exp2f(acc[4][0]));
    if (t == 1024) break;

    // ---- merged PW: lane e = b>>1 selects its tile's gates (16 cndmask) ----
    f32x4 g;
#pragma unroll
    for (int r = 0; r < 4; ++r) {
      const float t01 = (b & 2) ? acc[1][r] : acc[0][r];
      const float t23 = (b & 2) ? acc[3][r] : acc[2][r];
      const float t03 = (b & 4) ? t23 : t01;
      g[r] = (b & 8) ? acc[4][r] : t03;   // e>=5 -> acc[4] (bounded; unwritten)
    }
    // g: 0=i',1=f',2=g',3=o' (pre-scaled preacts)
    const float ei = __builtin_amdgcn_exp2f(g[0]);
    const float ef = __builtin_amdgcn_exp2f(g[1]);
    const float eg = __builtin_amdgcn_exp2f(g[2]);
    const float eo = __builtin_amdgcn_exp2f(g[3]);
    const float A   = 1.0f + ei;     // 1/i
    const float F   = 1.0f + ef;     // 1/f
    const float G1  = eg + 1.0f;
    const float Gm  = eg - 1.0f;     // g = Gm/G1
    const float AG  = A * G1;
    const float num = fmaf(cst, AG, Gm * F);
    const float cn  = num * __builtin_amdgcn_rcpf(F * AG);
    cst = cn;
    const float ec = __builtin_amdgcn_exp2f(TWOLOG2E * cn);
    const float hv = (ec - 1.0f) *
                     __builtin_amdgcn_rcpf((1.0f + eo) * (ec + 1.0f)); // o*tanh(c)
    if (wen) {                       // h(t) -> buf[(t+1)&1]
      _Float16* w = (t & 1) ? wp0 : wp1;
      *w = (_Float16)hv;
    }
    if (is_x && t < 1023) {          // x_{t+1} -> same buffer
      _Float16* xw = (t & 1) ? xw0 : xw1;
      *xw = xv;
    }
    __syncthreads();
  }
}

extern "C" void kernel_launch(void* const* d_in, const int* in_sizes, int n_in,
                              void* d_out, int out_size, void* d_ws, size_t ws_size,
                              hipStream_t stream) {
  const float* x     = (const float*)d_in[0];
  const float* W_ih  = (const float*)d_in[1];
  const float* W_hh  = (const float*)d_in[2];
  const float* b_ih  = (const float*)d_in[3];
  const float* b_hh  = (const float*)d_in[4];
  const float* W_out = (const float*)d_in[5];
  const float* b_out = (const float*)d_in[6];
  lstm_kernel<<<dim3(256), dim3(512), 0, stream>>>(
      x, W_ih, W_hh, b_ih, b_hh, W_out, b_out, (float*)d_out);
}